// Round 12
// baseline (447.417 us; speedup 1.0000x reference)
//
#include <hip/hip_runtime.h>

typedef unsigned short u16;
typedef unsigned int u32;
typedef __attribute__((ext_vector_type(8))) __bf16 bf16x8;
typedef __attribute__((ext_vector_type(4))) float f32x4;
typedef __attribute__((ext_vector_type(8))) u16 u16x8;
typedef __attribute__((ext_vector_type(4))) u16 u16x4;

typedef const __attribute__((address_space(1))) u32* gas_p;
typedef __attribute__((address_space(3))) u32* las_p;

__device__ __forceinline__ void gload16(const void* g, void* l) {
  __builtin_amdgcn_global_load_lds((gas_p)g, (las_p)l, 16, 0, 0);
}

__device__ __forceinline__ u16 f2bf(float f) {
  u32 u = __builtin_bit_cast(u32, f);
  u32 r = (u + 0x7fffu + ((u >> 16) & 1u)) >> 16;
  return (u16)r;
}

// ---- fused hs conversion: hs [16384][1024] f32 -> hs_bf (same layout) + hsT2 [4][1024][4096] ----
__global__ __launch_bounds__(256) void conv_hs(const float* __restrict__ in,
                                               u16* __restrict__ out_row,
                                               u16* __restrict__ out_t) {
  __shared__ u16 t[32][34];
  const int r0 = blockIdx.x * 32, c0 = blockIdx.y * 32;
  const int lx = threadIdx.x & 31, ly = threadIdx.x >> 5;  // ly: 0..7
#pragma unroll
  for (int i = 0; i < 4; ++i) {
    const int r = r0 + ly + i * 8;
    const u16 v = f2bf(in[(size_t)r * 1024 + c0 + lx]);
    out_row[(size_t)r * 1024 + c0 + lx] = v;
    t[ly + i * 8][lx] = v;
  }
  __syncthreads();
  const int b = r0 >> 12, s0 = r0 & 4095;
#pragma unroll
  for (int i = 0; i < 4; ++i)
    out_t[((size_t)b * 1024 + c0 + ly + i * 8) * 4096 + s0 + lx] = t[lx][ly + i * 8];
}

// ---- 4 weight matrices fp32 -> bf16, one launch ----
__global__ __launch_bounds__(256) void conv_w4(const float* __restrict__ a,
                                               const float* __restrict__ b,
                                               const float* __restrict__ c,
                                               const float* __restrict__ d,
                                               u16* __restrict__ out) {
  const float* src = blockIdx.y == 0 ? a : blockIdx.y == 1 ? b : blockIdx.y == 2 ? c : d;
  const int i = (blockIdx.x * 256 + threadIdx.x) * 4;
  const float4 v = *(const float4*)(src + i);
  u16x4 o = {f2bf(v.x), f2bf(v.y), f2bf(v.z), f2bf(v.w)};
  *(u16x4*)(out + (size_t)blockIdx.y * 1048576 + i) = o;
}

// ---- transpose + convert: in [4096][256] f32 -> out [256][4096] bf16 ----
__global__ __launch_bounds__(256) void transpose_conv(const float* __restrict__ in,
                                                      u16* __restrict__ out) {
  const int R = 4096, Cc = 256;
  __shared__ float t[32][33];
  const int r0 = blockIdx.x * 32, c0 = blockIdx.y * 32;
  const int lx = threadIdx.x & 31, ly = threadIdx.x >> 5;
#pragma unroll
  for (int i = 0; i < 4; ++i)
    t[ly + i * 8][lx] = in[(size_t)(r0 + ly + i * 8) * Cc + c0 + lx];
  __syncthreads();
#pragma unroll
  for (int i = 0; i < 4; ++i)
    out[(size_t)(c0 + ly + i * 8) * R + r0 + lx] = f2bf(t[lx][ly + i * 8]);
}

// ---------------- bf16 GEMM: C[M][N] = A[M][K] * B[N][K]^T ----------------
// 128x128 tile, BK=64, 4 waves (2x2), 4x4 frags, 32 MFMA/wave per barrier pair.
template <int OUTBF>
__global__ __launch_bounds__(256) void gemm_bt(const u16* __restrict__ A,
                                               const u16* __restrict__ B,
                                               void* __restrict__ C, int M, int N,
                                               int K) {
  __shared__ u16 lds[2][128 * 64];  // 32 KiB total
  const int tid = threadIdx.x, l = tid & 63, w = tid >> 6;
  const int m0 = blockIdx.x * 128, n0 = blockIdx.y * 128;
  const int wr = w >> 1, wc = w & 1;
  f32x4 acc[4][4] = {};
  for (int k0 = 0; k0 < K; k0 += 64) {
#pragma unroll
    for (int i = 0; i < 4; ++i) {
      const int c = i * 256 + tid;
      const int row = c >> 3;
      const int scb = ((c & 7) << 4) ^ ((row & 7) << 4);
      gload16((const char*)A + ((size_t)(m0 + row) * K + k0) * 2 + scb,
              (char*)&lds[0][0] + (size_t)(i * 256 + w * 64) * 16);
      gload16((const char*)B + ((size_t)(n0 + row) * K + k0) * 2 + scb,
              (char*)&lds[1][0] + (size_t)(i * 256 + w * 64) * 16);
    }
    __syncthreads();
#pragma unroll
    for (int kk = 0; kk < 2; ++kk) {
      bf16x8 af[4], bf[4];
#pragma unroll
      for (int f = 0; f < 4; ++f) {
        const int ra = wr * 64 + f * 16 + (l & 15);
        af[f] = *(const bf16x8*)((const char*)&lds[0][0] + ra * 128 +
                                 (((l >> 4) * 16 + kk * 64) ^ ((ra & 7) << 4)));
        const int rb = wc * 64 + f * 16 + (l & 15);
        bf[f] = *(const bf16x8*)((const char*)&lds[1][0] + rb * 128 +
                                 (((l >> 4) * 16 + kk * 64) ^ ((rb & 7) << 4)));
      }
#pragma unroll
      for (int mf = 0; mf < 4; ++mf)
#pragma unroll
        for (int nf = 0; nf < 4; ++nf)
          acc[mf][nf] = __builtin_amdgcn_mfma_f32_16x16x32_bf16(af[mf], bf[nf],
                                                                acc[mf][nf], 0, 0, 0);
    }
    __syncthreads();
  }
#pragma unroll
  for (int mf = 0; mf < 4; ++mf) {
    const int rbase = m0 + wr * 64 + mf * 16 + ((l >> 4) << 2);
#pragma unroll
    for (int nf = 0; nf < 4; ++nf) {
      const int cc = n0 + wc * 64 + nf * 16 + (l & 15);
#pragma unroll
      for (int j = 0; j < 4; ++j) {
        if (OUTBF)
          ((u16*)C)[(size_t)(rbase + j) * N + cc] = f2bf(acc[mf][nf][j]);
        else
          ((float*)C)[(size_t)(rbase + j) * N + cc] = acc[mf][nf][j];
      }
    }
  }
}

// ---- Linformer projection as pure BT GEMM: hsEF[b][m][n] = sum_k EFt[m][k]*hsT2[b][n][k] ----
// 64x128 tile, BK=64, 4 waves (2x2), 2x4 frags.
__global__ __launch_bounds__(256) void proj64(const u16* __restrict__ EFt,
                                              const u16* __restrict__ hsT2,
                                              u16* __restrict__ hsEF) {
  __shared__ u16 lA[64 * 64], lB[128 * 64];  // 8 KiB + 16 KiB
  const int tid = threadIdx.x, l = tid & 63, w = tid >> 6;
  const int m0 = blockIdx.x * 64, n0 = blockIdx.y * 128, b = blockIdx.z;
  const u16* Bp = hsT2 + (size_t)b * 1024 * 4096;
  const int wr = w >> 1, wc = w & 1;
  f32x4 acc[2][4] = {};
  for (int k0 = 0; k0 < 4096; k0 += 64) {
#pragma unroll
    for (int i = 0; i < 2; ++i) {  // A: 64 rows x 128B = 512 chunks
      const int c = i * 256 + tid;
      const int row = c >> 3;
      const int scb = ((c & 7) << 4) ^ ((row & 7) << 4);
      gload16((const char*)EFt + ((size_t)(m0 + row) * 4096 + k0) * 2 + scb,
              (char*)lA + (size_t)(i * 256 + w * 64) * 16);
    }
#pragma unroll
    for (int i = 0; i < 4; ++i) {  // B: 128 rows x 128B = 1024 chunks
      const int c = i * 256 + tid;
      const int row = c >> 3;
      const int scb = ((c & 7) << 4) ^ ((row & 7) << 4);
      gload16((const char*)Bp + ((size_t)(n0 + row) * 4096 + k0) * 2 + scb,
              (char*)lB + (size_t)(i * 256 + w * 64) * 16);
    }
    __syncthreads();
#pragma unroll
    for (int kk = 0; kk < 2; ++kk) {
      bf16x8 af[2], bf[4];
#pragma unroll
      for (int f = 0; f < 2; ++f) {
        const int ra = wr * 32 + f * 16 + (l & 15);
        af[f] = *(const bf16x8*)((const char*)lA + ra * 128 +
                                 (((l >> 4) * 16 + kk * 64) ^ ((ra & 7) << 4)));
      }
#pragma unroll
      for (int f = 0; f < 4; ++f) {
        const int rb = wc * 64 + f * 16 + (l & 15);
        bf[f] = *(const bf16x8*)((const char*)lB + rb * 128 +
                                 (((l >> 4) * 16 + kk * 64) ^ ((rb & 7) << 4)));
      }
#pragma unroll
      for (int mf = 0; mf < 2; ++mf)
#pragma unroll
        for (int nf = 0; nf < 4; ++nf)
          acc[mf][nf] = __builtin_amdgcn_mfma_f32_16x16x32_bf16(af[mf], bf[nf],
                                                                acc[mf][nf], 0, 0, 0);
    }
    __syncthreads();
  }
#pragma unroll
  for (int mf = 0; mf < 2; ++mf) {
    const int rbase = m0 + wr * 32 + mf * 16 + ((l >> 4) << 2);
#pragma unroll
    for (int nf = 0; nf < 4; ++nf) {
      const int cc = n0 + wc * 64 + nf * 16 + (l & 15);
#pragma unroll
      for (int j = 0; j < 4; ++j)
        hsEF[((size_t)b * 512 + rbase + j) * 1024 + cc] = f2bf(acc[mf][nf][j]);
    }
  }
}

// ---- combined K'/V' weight application: A = hsEF flat [2048][1024], B = Wk or Wv ----
// 64x128 tile, BK=64. grid (32,8)=256 blocks.
__global__ __launch_bounds__(256) void gemm_kv(const u16* __restrict__ hsEF,
                                               const u16* __restrict__ Wk,
                                               const u16* __restrict__ Wv,
                                               u16* __restrict__ kproj,
                                               u16* __restrict__ vprojT) {
  __shared__ u16 lA[64 * 64], lB[128 * 64];
  const int tid = threadIdx.x, l = tid & 63, w = tid >> 6;
  const int m0 = blockIdx.x * 64, n0 = blockIdx.y * 128;
  const int b = m0 >> 9, half = (m0 >> 8) & 1;
  const u16* Bp = half ? Wv : Wk;
  const int wr = w >> 1, wc = w & 1;
  f32x4 acc[2][4] = {};
  for (int k0 = 0; k0 < 1024; k0 += 64) {
#pragma unroll
    for (int i = 0; i < 2; ++i) {
      const int c = i * 256 + tid;
      const int row = c >> 3;
      const int scb = ((c & 7) << 4) ^ ((row & 7) << 4);
      gload16((const char*)hsEF + ((size_t)(m0 + row) * 1024 + k0) * 2 + scb,
              (char*)lA + (size_t)(i * 256 + w * 64) * 16);
    }
#pragma unroll
    for (int i = 0; i < 4; ++i) {
      const int c = i * 256 + tid;
      const int row = c >> 3;
      const int scb = ((c & 7) << 4) ^ ((row & 7) << 4);
      gload16((const char*)Bp + ((size_t)(n0 + row) * 1024 + k0) * 2 + scb,
              (char*)lB + (size_t)(i * 256 + w * 64) * 16);
    }
    __syncthreads();
#pragma unroll
    for (int kk = 0; kk < 2; ++kk) {
      bf16x8 af[2], bf[4];
#pragma unroll
      for (int f = 0; f < 2; ++f) {
        const int ra = wr * 32 + f * 16 + (l & 15);
        af[f] = *(const bf16x8*)((const char*)lA + ra * 128 +
                                 (((l >> 4) * 16 + kk * 64) ^ ((ra & 7) << 4)));
      }
#pragma unroll
      for (int f = 0; f < 4; ++f) {
        const int rb = wc * 64 + f * 16 + (l & 15);
        bf[f] = *(const bf16x8*)((const char*)lB + rb * 128 +
                                 (((l >> 4) * 16 + kk * 64) ^ ((rb & 7) << 4)));
      }
#pragma unroll
      for (int mf = 0; mf < 2; ++mf)
#pragma unroll
        for (int nf = 0; nf < 4; ++nf)
          acc[mf][nf] = __builtin_amdgcn_mfma_f32_16x16x32_bf16(af[mf], bf[nf],
                                                                acc[mf][nf], 0, 0, 0);
    }
    __syncthreads();
  }
#pragma unroll
  for (int mf = 0; mf < 2; ++mf) {
    const int kp0 = (m0 & 255) + wr * 32 + mf * 16 + ((l >> 4) << 2);
#pragma unroll
    for (int nf = 0; nf < 4; ++nf) {
      const int n = n0 + wc * 64 + nf * 16 + (l & 15);
      if (!half) {
#pragma unroll
        for (int j = 0; j < 4; ++j)
          kproj[((size_t)b * 256 + kp0 + j) * 1024 + n] = f2bf(acc[mf][nf][j]);
      } else {
        u16x4 o = {f2bf(acc[mf][nf][0]), f2bf(acc[mf][nf][1]), f2bf(acc[mf][nf][2]),
                   f2bf(acc[mf][nf][3])};
        *(u16x4*)(vprojT + ((size_t)b * 1024 + n) * 256 + kp0) = o;
      }
    }
  }
}

// ---------------- fused attention v2 ----------------
// K'/V' fragments read DIRECTLY from global (L2-resident: 64 KB per (b,h), reused by
// 64 q-tile blocks). LDS holds only per-wave P (32 KiB/block -> higher occupancy).
// Softmax normalization deferred to the fp32 epilogue (exact algebra).
__global__ __launch_bounds__(256) void attn_kernel(const u16* __restrict__ qmat,
                                                   const u16* __restrict__ kproj,
                                                   const u16* __restrict__ vprojT,
                                                   u16* __restrict__ aout) {
  __shared__ u16 smem[16384];  // 32 KiB: P only, 8 KiB per wave
  const int tid = threadIdx.x, l = tid & 63, w = tid >> 6;
  const int qt = blockIdx.x, h = blockIdx.y, b = blockIdx.z;
  const int qbase = qt * 64;

  // ---- Q fragments straight from global (16B per lane) ----
  const u16* qrow =
      qmat + ((size_t)(b * 4096 + qbase + w * 16 + (l & 15))) * 1024 + h * 64;
  bf16x8 qa[2];
#pragma unroll
  for (int kf = 0; kf < 2; ++kf)
    qa[kf] = *(const bf16x8*)(qrow + kf * 32 + (l >> 4) * 8);

  // ---- S = Q K'^T: B-fragments straight from global (L2-hit) ----
  const u16* kbase = kproj + ((size_t)(b * 256)) * 1024 + h * 64;
  f32x4 s[16] = {};
#pragma unroll
  for (int nf = 0; nf < 16; ++nf) {
    const int kr = nf * 16 + (l & 15);
#pragma unroll
    for (int kf = 0; kf < 2; ++kf) {
      const bf16x8 kb =
          *(const bf16x8*)(kbase + (size_t)kr * 1024 + kf * 32 + (l >> 4) * 8);
      s[nf] = __builtin_amdgcn_mfma_f32_16x16x32_bf16(qa[kf], kb, s[nf], 0, 0, 0);
    }
  }

  // ---- wave-parallel softmax (scale 1/8 in exp), UNNORMALIZED P ----
  float mx[4] = {-1e30f, -1e30f, -1e30f, -1e30f}, sum[4] = {0.f, 0.f, 0.f, 0.f};
#pragma unroll
  for (int j = 0; j < 4; ++j) {
#pragma unroll
    for (int nf = 0; nf < 16; ++nf) mx[j] = fmaxf(mx[j], s[nf][j]);
#pragma unroll
    for (int m = 1; m < 16; m <<= 1) mx[j] = fmaxf(mx[j], __shfl_xor(mx[j], m, 64));
  }
#pragma unroll
  for (int nf = 0; nf < 16; ++nf)
#pragma unroll
    for (int j = 0; j < 4; ++j) {
      const float e = __expf((s[nf][j] - mx[j]) * 0.125f);
      s[nf][j] = e;
      sum[j] += e;
    }
#pragma unroll
  for (int j = 0; j < 4; ++j)
#pragma unroll
    for (int m = 1; m < 16; m <<= 1) sum[j] += __shfl_xor(sum[j], m, 64);

  // rsum for this lane's epilogue q-row (q = l&15): row r's sum lives in
  // group g=r>>2 (lanes g*16..), slot j=r&3. Broadcast all 4 slots, select.
  float bs0 = __shfl(sum[0], ((l & 15) >> 2) << 4, 64);
  float bs1 = __shfl(sum[1], ((l & 15) >> 2) << 4, 64);
  float bs2 = __shfl(sum[2], ((l & 15) >> 2) << 4, 64);
  float bs3 = __shfl(sum[3], ((l & 15) >> 2) << 4, 64);
  const float r01 = (l & 1) ? bs1 : bs0;
  const float r23 = (l & 1) ? bs3 : bs2;
  const float rs = 1.0f / ((l & 2) ? r23 : r01);

  // ---- write unnormalized P (bf16) into per-wave LDS region, swizzled ----
  u16* Pw = smem + w * 4096;  // 16 rows x 512B
#pragma unroll
  for (int nf = 0; nf < 16; ++nf) {
    const int col = nf * 16 + (l & 15);
#pragma unroll
    for (int j = 0; j < 4; ++j) {
      const int row = (l >> 4) * 4 + j;
      *(u16*)((char*)Pw + row * 512 + ((col * 2) ^ (row << 4))) = f2bf(s[nf][j]);
    }
  }
  __syncthreads();  // LDS write->read ordering (wave-private regions; cheap)

  // ---- O^T[d][q] = V'^T * P^T: A-fragments straight from global (L2-hit) ----
  const u16* vbase = vprojT + ((size_t)(b * 1024 + h * 64)) * 256;
  f32x4 o[4] = {};
#pragma unroll
  for (int kf = 0; kf < 8; ++kf) {
    const int q = l & 15;
    const bf16x8 pb = *(const bf16x8*)((const char*)Pw + q * 512 +
                                       ((kf * 64 + (l >> 4) * 16) ^ (q << 4)));
#pragma unroll
    for (int mf = 0; mf < 4; ++mf) {
      const int d = mf * 16 + (l & 15);
      const bf16x8 va =
          *(const bf16x8*)(vbase + (size_t)d * 256 + kf * 32 + (l >> 4) * 8);
      o[mf] = __builtin_amdgcn_mfma_f32_16x16x32_bf16(va, pb, o[mf], 0, 0, 0);
    }
  }

  // ---- epilogue: scale by 1/sum (deferred normalization), write out ----
#pragma unroll
  for (int mf = 0; mf < 4; ++mf) {
    const int d0 = mf * 16 + ((l >> 4) << 2);
    const int srow = b * 4096 + qbase + w * 16 + (l & 15);
    u16x4 ov = {f2bf(o[mf][0] * rs), f2bf(o[mf][1] * rs), f2bf(o[mf][2] * rs),
                f2bf(o[mf][3] * rs)};
    *(u16x4*)(aout + (size_t)srow * 1024 + h * 64 + d0) = ov;
  }
}

// ---------------- host launch ----------------
extern "C" void kernel_launch(void* const* d_in, const int* in_sizes, int n_in,
                              void* d_out, int out_size, void* d_ws, size_t ws_size,
                              hipStream_t stream) {
  const float* hs = (const float*)d_in[0];
  const float* Wq = (const float*)d_in[1];
  const float* Wk = (const float*)d_in[2];
  const float* Wv = (const float*)d_in[3];
  const float* Wo = (const float*)d_in[4];
  const float* E = (const float*)d_in[5];
  const float* F = (const float*)d_in[6];

  // Workspace layout: peak 116 MiB (proven in R2/R7/R11).
  // aout ALIASES hsT2: hsT2 dead after proj64; aout first written by attn_kernel.
  char* ws = (char*)d_ws;
  u16* hs_bf = (u16*)(ws + 0);              // 32 MiB [16384][1024]
  u16* hsT2 = (u16*)(ws + 33554432);        // 32 MiB [4][1024][4096]
  u16* aout = hsT2;                         // 32 MiB [16384][1024] (alias)
  u16* qout = (u16*)(ws + 67108864);        // 32 MiB [16384][1024]
  u16* Wall = (u16*)(ws + 100663296);       // 8 MiB  Wq|Wk|Wv|Wo bf16
  u16* EFt = (u16*)(ws + 109051904);        // 4 MiB  [512][4096]
  u16* hsEF = (u16*)(ws + 113246208);       // 4 MiB  [4][512][1024]
  u16* kproj = (u16*)(ws + 117440512);      // 2 MiB  [4][256][1024]
  u16* vprojT = (u16*)(ws + 119537664);     // 2 MiB  [4][1024][256]

  conv_hs<<<dim3(512, 32), 256, 0, stream>>>(hs, hs_bf, hsT2);
  conv_w4<<<dim3(1024, 4), 256, 0, stream>>>(Wq, Wk, Wv, Wo, Wall);
  transpose_conv<<<dim3(128, 8), 256, 0, stream>>>(E, EFt);
  transpose_conv<<<dim3(128, 8), 256, 0, stream>>>(F, EFt + (size_t)256 * 4096);

  // q = hs @ Wq^T
  gemm_bt<1><<<dim3(128, 8), 256, 0, stream>>>(hs_bf, Wall, qout, 16384, 1024, 1024);
  // hsEF[b] = [E;F]^T @ hs[b]
  proj64<<<dim3(8, 8, 4), 256, 0, stream>>>(EFt, hsT2, hsEF);
  // kproj = hsE @ Wk^T ; vprojT = (hsF @ Wv^T)^T
  gemm_kv<<<dim3(32, 8), 256, 0, stream>>>(hsEF, Wall + 1048576, Wall + 2097152,
                                           kproj, vprojT);
  attn_kernel<<<dim3(64, 16, 4), 256, 0, stream>>>(qout, kproj, vprojT, aout);
  // out = attn_out @ Wo^T (fp32 epilogue)
  gemm_bt<0><<<dim3(128, 8), 256, 0, stream>>>(aout, Wall + 3145728, d_out, 16384,
                                               1024, 1024);
}

// Round 13
// 380.816 us; speedup vs baseline: 1.1749x; 1.1749x over previous
//
#include <hip/hip_runtime.h>

typedef unsigned short u16;
typedef unsigned int u32;
typedef __attribute__((ext_vector_type(8))) __bf16 bf16x8;
typedef __attribute__((ext_vector_type(4))) float f32x4;
typedef __attribute__((ext_vector_type(8))) u16 u16x8;
typedef __attribute__((ext_vector_type(4))) u16 u16x4;

typedef const __attribute__((address_space(1))) u32* gas_p;
typedef __attribute__((address_space(3))) u32* las_p;

__device__ __forceinline__ void gload16(const void* g, void* l) {
  __builtin_amdgcn_global_load_lds((gas_p)g, (las_p)l, 16, 0, 0);
}

__device__ __forceinline__ u16 f2bf(float f) {
  u32 u = __builtin_bit_cast(u32, f);
  u32 r = (u + 0x7fffu + ((u >> 16) & 1u)) >> 16;
  return (u16)r;
}

// ---- fused hs conversion: hs [16384][1024] f32 -> hs_bf (same layout) + hsT2 [4][1024][4096] ----
__global__ __launch_bounds__(256) void conv_hs(const float* __restrict__ in,
                                               u16* __restrict__ out_row,
                                               u16* __restrict__ out_t) {
  __shared__ u16 t[32][34];
  const int r0 = blockIdx.x * 32, c0 = blockIdx.y * 32;
  const int lx = threadIdx.x & 31, ly = threadIdx.x >> 5;  // ly: 0..7
#pragma unroll
  for (int i = 0; i < 4; ++i) {
    const int r = r0 + ly + i * 8;
    const u16 v = f2bf(in[(size_t)r * 1024 + c0 + lx]);
    out_row[(size_t)r * 1024 + c0 + lx] = v;
    t[ly + i * 8][lx] = v;
  }
  __syncthreads();
  const int b = r0 >> 12, s0 = r0 & 4095;
#pragma unroll
  for (int i = 0; i < 4; ++i)
    out_t[((size_t)b * 1024 + c0 + ly + i * 8) * 4096 + s0 + lx] = t[lx][ly + i * 8];
}

// ---- 4 weight matrices fp32 -> bf16, one launch ----
__global__ __launch_bounds__(256) void conv_w4(const float* __restrict__ a,
                                               const float* __restrict__ b,
                                               const float* __restrict__ c,
                                               const float* __restrict__ d,
                                               u16* __restrict__ out) {
  const float* src = blockIdx.y == 0 ? a : blockIdx.y == 1 ? b : blockIdx.y == 2 ? c : d;
  const int i = (blockIdx.x * 256 + threadIdx.x) * 4;
  const float4 v = *(const float4*)(src + i);
  u16x4 o = {f2bf(v.x), f2bf(v.y), f2bf(v.z), f2bf(v.w)};
  *(u16x4*)(out + (size_t)blockIdx.y * 1048576 + i) = o;
}

// ---- transpose + convert: in [4096][256] f32 -> out [256][4096] bf16 ----
__global__ __launch_bounds__(256) void transpose_conv(const float* __restrict__ in,
                                                      u16* __restrict__ out) {
  const int R = 4096, Cc = 256;
  __shared__ float t[32][33];
  const int r0 = blockIdx.x * 32, c0 = blockIdx.y * 32;
  const int lx = threadIdx.x & 31, ly = threadIdx.x >> 5;
#pragma unroll
  for (int i = 0; i < 4; ++i)
    t[ly + i * 8][lx] = in[(size_t)(r0 + ly + i * 8) * Cc + c0 + lx];
  __syncthreads();
#pragma unroll
  for (int i = 0; i < 4; ++i)
    out[(size_t)(c0 + ly + i * 8) * R + r0 + lx] = f2bf(t[lx][ly + i * 8]);
}

// ---------------- bf16 GEMM: C[M][N] = A[M][K] * B[N][K]^T ----------------
// 128x128 tile, BK=64, 4 waves (2x2), 4x4 frags, 32 MFMA/wave per barrier pair.
template <int OUTBF>
__global__ __launch_bounds__(256) void gemm_bt(const u16* __restrict__ A,
                                               const u16* __restrict__ B,
                                               void* __restrict__ C, int M, int N,
                                               int K) {
  __shared__ u16 lds[2][128 * 64];  // 32 KiB total
  const int tid = threadIdx.x, l = tid & 63, w = tid >> 6;
  const int m0 = blockIdx.x * 128, n0 = blockIdx.y * 128;
  const int wr = w >> 1, wc = w & 1;
  f32x4 acc[4][4] = {};
  for (int k0 = 0; k0 < K; k0 += 64) {
#pragma unroll
    for (int i = 0; i < 4; ++i) {
      const int c = i * 256 + tid;
      const int row = c >> 3;
      const int scb = ((c & 7) << 4) ^ ((row & 7) << 4);
      gload16((const char*)A + ((size_t)(m0 + row) * K + k0) * 2 + scb,
              (char*)&lds[0][0] + (size_t)(i * 256 + w * 64) * 16);
      gload16((const char*)B + ((size_t)(n0 + row) * K + k0) * 2 + scb,
              (char*)&lds[1][0] + (size_t)(i * 256 + w * 64) * 16);
    }
    __syncthreads();
#pragma unroll
    for (int kk = 0; kk < 2; ++kk) {
      bf16x8 af[4], bf[4];
#pragma unroll
      for (int f = 0; f < 4; ++f) {
        const int ra = wr * 64 + f * 16 + (l & 15);
        af[f] = *(const bf16x8*)((const char*)&lds[0][0] + ra * 128 +
                                 (((l >> 4) * 16 + kk * 64) ^ ((ra & 7) << 4)));
        const int rb = wc * 64 + f * 16 + (l & 15);
        bf[f] = *(const bf16x8*)((const char*)&lds[1][0] + rb * 128 +
                                 (((l >> 4) * 16 + kk * 64) ^ ((rb & 7) << 4)));
      }
#pragma unroll
      for (int mf = 0; mf < 4; ++mf)
#pragma unroll
        for (int nf = 0; nf < 4; ++nf)
          acc[mf][nf] = __builtin_amdgcn_mfma_f32_16x16x32_bf16(af[mf], bf[nf],
                                                                acc[mf][nf], 0, 0, 0);
    }
    __syncthreads();
  }
#pragma unroll
  for (int mf = 0; mf < 4; ++mf) {
    const int rbase = m0 + wr * 64 + mf * 16 + ((l >> 4) << 2);
#pragma unroll
    for (int nf = 0; nf < 4; ++nf) {
      const int cc = n0 + wc * 64 + nf * 16 + (l & 15);
#pragma unroll
      for (int j = 0; j < 4; ++j) {
        if (OUTBF)
          ((u16*)C)[(size_t)(rbase + j) * N + cc] = f2bf(acc[mf][nf][j]);
        else
          ((float*)C)[(size_t)(rbase + j) * N + cc] = acc[mf][nf][j];
      }
    }
  }
}

// ---- Linformer projection as pure BT GEMM: hsEF[b][m][n] = sum_k EFt[m][k]*hsT2[b][n][k] ----
// 64x128 tile, BK=64, 4 waves (2x2), 2x4 frags.
__global__ __launch_bounds__(256) void proj64(const u16* __restrict__ EFt,
                                              const u16* __restrict__ hsT2,
                                              u16* __restrict__ hsEF) {
  __shared__ u16 lA[64 * 64], lB[128 * 64];  // 8 KiB + 16 KiB
  const int tid = threadIdx.x, l = tid & 63, w = tid >> 6;
  const int m0 = blockIdx.x * 64, n0 = blockIdx.y * 128, b = blockIdx.z;
  const u16* Bp = hsT2 + (size_t)b * 1024 * 4096;
  const int wr = w >> 1, wc = w & 1;
  f32x4 acc[2][4] = {};
  for (int k0 = 0; k0 < 4096; k0 += 64) {
#pragma unroll
    for (int i = 0; i < 2; ++i) {  // A: 64 rows x 128B = 512 chunks
      const int c = i * 256 + tid;
      const int row = c >> 3;
      const int scb = ((c & 7) << 4) ^ ((row & 7) << 4);
      gload16((const char*)EFt + ((size_t)(m0 + row) * 4096 + k0) * 2 + scb,
              (char*)lA + (size_t)(i * 256 + w * 64) * 16);
    }
#pragma unroll
    for (int i = 0; i < 4; ++i) {  // B: 128 rows x 128B = 1024 chunks
      const int c = i * 256 + tid;
      const int row = c >> 3;
      const int scb = ((c & 7) << 4) ^ ((row & 7) << 4);
      gload16((const char*)Bp + ((size_t)(n0 + row) * 4096 + k0) * 2 + scb,
              (char*)lB + (size_t)(i * 256 + w * 64) * 16);
    }
    __syncthreads();
#pragma unroll
    for (int kk = 0; kk < 2; ++kk) {
      bf16x8 af[2], bf[4];
#pragma unroll
      for (int f = 0; f < 2; ++f) {
        const int ra = wr * 32 + f * 16 + (l & 15);
        af[f] = *(const bf16x8*)((const char*)lA + ra * 128 +
                                 (((l >> 4) * 16 + kk * 64) ^ ((ra & 7) << 4)));
      }
#pragma unroll
      for (int f = 0; f < 4; ++f) {
        const int rb = wc * 64 + f * 16 + (l & 15);
        bf[f] = *(const bf16x8*)((const char*)lB + rb * 128 +
                                 (((l >> 4) * 16 + kk * 64) ^ ((rb & 7) << 4)));
      }
#pragma unroll
      for (int mf = 0; mf < 2; ++mf)
#pragma unroll
        for (int nf = 0; nf < 4; ++nf)
          acc[mf][nf] = __builtin_amdgcn_mfma_f32_16x16x32_bf16(af[mf], bf[nf],
                                                                acc[mf][nf], 0, 0, 0);
    }
    __syncthreads();
  }
#pragma unroll
  for (int mf = 0; mf < 2; ++mf) {
    const int rbase = m0 + wr * 32 + mf * 16 + ((l >> 4) << 2);
#pragma unroll
    for (int nf = 0; nf < 4; ++nf) {
      const int cc = n0 + wc * 64 + nf * 16 + (l & 15);
#pragma unroll
      for (int j = 0; j < 4; ++j)
        hsEF[((size_t)b * 512 + rbase + j) * 1024 + cc] = f2bf(acc[mf][nf][j]);
    }
  }
}

// ---- combined K'/V' weight application: A = hsEF flat [2048][1024], B = Wk or Wv ----
// 64x128 tile, BK=64. grid (32,8)=256 blocks.
__global__ __launch_bounds__(256) void gemm_kv(const u16* __restrict__ hsEF,
                                               const u16* __restrict__ Wk,
                                               const u16* __restrict__ Wv,
                                               u16* __restrict__ kproj,
                                               u16* __restrict__ vprojT) {
  __shared__ u16 lA[64 * 64], lB[128 * 64];
  const int tid = threadIdx.x, l = tid & 63, w = tid >> 6;
  const int m0 = blockIdx.x * 64, n0 = blockIdx.y * 128;
  const int b = m0 >> 9, half = (m0 >> 8) & 1;
  const u16* Bp = half ? Wv : Wk;
  const int wr = w >> 1, wc = w & 1;
  f32x4 acc[2][4] = {};
  for (int k0 = 0; k0 < 1024; k0 += 64) {
#pragma unroll
    for (int i = 0; i < 2; ++i) {
      const int c = i * 256 + tid;
      const int row = c >> 3;
      const int scb = ((c & 7) << 4) ^ ((row & 7) << 4);
      gload16((const char*)hsEF + ((size_t)(m0 + row) * 1024 + k0) * 2 + scb,
              (char*)lA + (size_t)(i * 256 + w * 64) * 16);
    }
#pragma unroll
    for (int i = 0; i < 4; ++i) {
      const int c = i * 256 + tid;
      const int row = c >> 3;
      const int scb = ((c & 7) << 4) ^ ((row & 7) << 4);
      gload16((const char*)Bp + ((size_t)(n0 + row) * 1024 + k0) * 2 + scb,
              (char*)lB + (size_t)(i * 256 + w * 64) * 16);
    }
    __syncthreads();
#pragma unroll
    for (int kk = 0; kk < 2; ++kk) {
      bf16x8 af[2], bf[4];
#pragma unroll
      for (int f = 0; f < 2; ++f) {
        const int ra = wr * 32 + f * 16 + (l & 15);
        af[f] = *(const bf16x8*)((const char*)lA + ra * 128 +
                                 (((l >> 4) * 16 + kk * 64) ^ ((ra & 7) << 4)));
      }
#pragma unroll
      for (int f = 0; f < 4; ++f) {
        const int rb = wc * 64 + f * 16 + (l & 15);
        bf[f] = *(const bf16x8*)((const char*)lB + rb * 128 +
                                 (((l >> 4) * 16 + kk * 64) ^ ((rb & 7) << 4)));
      }
#pragma unroll
      for (int mf = 0; mf < 2; ++mf)
#pragma unroll
        for (int nf = 0; nf < 4; ++nf)
          acc[mf][nf] = __builtin_amdgcn_mfma_f32_16x16x32_bf16(af[mf], bf[nf],
                                                                acc[mf][nf], 0, 0, 0);
    }
    __syncthreads();
  }
#pragma unroll
  for (int mf = 0; mf < 2; ++mf) {
    const int kp0 = (m0 & 255) + wr * 32 + mf * 16 + ((l >> 4) << 2);
#pragma unroll
    for (int nf = 0; nf < 4; ++nf) {
      const int n = n0 + wc * 64 + nf * 16 + (l & 15);
      if (!half) {
#pragma unroll
        for (int j = 0; j < 4; ++j)
          kproj[((size_t)b * 256 + kp0 + j) * 1024 + n] = f2bf(acc[mf][nf][j]);
      } else {
        u16x4 o = {f2bf(acc[mf][nf][0]), f2bf(acc[mf][nf][1]), f2bf(acc[mf][nf][2]),
                   f2bf(acc[mf][nf][3])};
        *(u16x4*)(vprojT + ((size_t)b * 1024 + n) * 256 + kp0) = o;
      }
    }
  }
}

// ---------------- fused attention v3: staged LDS (R11 structure) + 2 q-tiles/block ----
// Stage K'/V' ONCE per (b,h,128-q-rows); both tiles' QK^T share each K'-fragment read.
// P region (wave-private, overlays K') reused sequentially for tile0 then tile1.
// Deferred softmax normalization (proven in R12).
__global__ __launch_bounds__(256) void attn_kernel(const u16* __restrict__ qmat,
                                                   const u16* __restrict__ kproj,
                                                   const u16* __restrict__ vprojT,
                                                   u16* __restrict__ aout) {
  __shared__ u16 smem[32768];  // 64KB: [0,32KB) K'/P union, [32KB,64KB) V'^T
  const int tid = threadIdx.x, l = tid & 63, w = tid >> 6;
  const int qt = blockIdx.x, h = blockIdx.y, b = blockIdx.z;
  const int qbase = qt * 128;

#pragma unroll
  for (int i = 0; i < 8; ++i) {  // K' [256][128B], swz (row&7)<<4
    const int c = i * 256 + tid;
    const int row = c >> 3;
    const int scb = ((c & 7) << 4) ^ ((row & 7) << 4);
    gload16((const char*)kproj + (((size_t)(b * 256 + row)) * 1024 + h * 64) * 2 + scb,
            (char*)smem + (size_t)(i * 256 + w * 64) * 16);
  }
#pragma unroll
  for (int i = 0; i < 8; ++i) {  // V'^T [64][512B], swz (d&31)<<4
    const int c = i * 256 + tid;
    const int d = c >> 5;
    const int scb = ((c & 31) << 4) ^ ((d & 31) << 4);
    gload16((const char*)vprojT + ((size_t)(b * 1024 + h * 64 + d)) * 256 * 2 + scb,
            (char*)smem + 32768 + (size_t)(i * 256 + w * 64) * 16);
  }
  __syncthreads();

  // ---- Q fragments for both tiles (16B per lane) ----
  bf16x8 qa[2][2];
#pragma unroll
  for (int t = 0; t < 2; ++t) {
    const u16* qrow =
        qmat + ((size_t)(b * 4096 + qbase + t * 64 + w * 16 + (l & 15))) * 1024 + h * 64;
#pragma unroll
    for (int kf = 0; kf < 2; ++kf)
      qa[t][kf] = *(const bf16x8*)(qrow + kf * 32 + (l >> 4) * 8);
  }

  // ---- S = Q K'^T for both tiles, sharing each K'-fragment read ----
  f32x4 s0[16] = {}, s1[16] = {};
#pragma unroll
  for (int nf = 0; nf < 16; ++nf) {
    const int kr = nf * 16 + (l & 15);
#pragma unroll
    for (int kf = 0; kf < 2; ++kf) {
      const bf16x8 kb = *(const bf16x8*)((const char*)smem + kr * 128 +
                                         ((kf * 64 + (l >> 4) * 16) ^ ((kr & 7) << 4)));
      s0[nf] = __builtin_amdgcn_mfma_f32_16x16x32_bf16(qa[0][kf], kb, s0[nf], 0, 0, 0);
      s1[nf] = __builtin_amdgcn_mfma_f32_16x16x32_bf16(qa[1][kf], kb, s1[nf], 0, 0, 0);
    }
  }

  // ---- wave-parallel softmax both tiles (scale 1/8 in exp), UNNORMALIZED ----
  float rs0, rs1;
  {
    float mx[4] = {-1e30f, -1e30f, -1e30f, -1e30f}, sum[4] = {0.f, 0.f, 0.f, 0.f};
#pragma unroll
    for (int j = 0; j < 4; ++j) {
#pragma unroll
      for (int nf = 0; nf < 16; ++nf) mx[j] = fmaxf(mx[j], s0[nf][j]);
#pragma unroll
      for (int m = 1; m < 16; m <<= 1) mx[j] = fmaxf(mx[j], __shfl_xor(mx[j], m, 64));
    }
#pragma unroll
    for (int nf = 0; nf < 16; ++nf)
#pragma unroll
      for (int j = 0; j < 4; ++j) {
        const float e = __expf((s0[nf][j] - mx[j]) * 0.125f);
        s0[nf][j] = e;
        sum[j] += e;
      }
#pragma unroll
    for (int j = 0; j < 4; ++j)
#pragma unroll
      for (int m = 1; m < 16; m <<= 1) sum[j] += __shfl_xor(sum[j], m, 64);
    const float bs0 = __shfl(sum[0], ((l & 15) >> 2) << 4, 64);
    const float bs1 = __shfl(sum[1], ((l & 15) >> 2) << 4, 64);
    const float bs2 = __shfl(sum[2], ((l & 15) >> 2) << 4, 64);
    const float bs3 = __shfl(sum[3], ((l & 15) >> 2) << 4, 64);
    const float r01 = (l & 1) ? bs1 : bs0;
    const float r23 = (l & 1) ? bs3 : bs2;
    rs0 = 1.0f / ((l & 2) ? r23 : r01);
  }
  {
    float mx[4] = {-1e30f, -1e30f, -1e30f, -1e30f}, sum[4] = {0.f, 0.f, 0.f, 0.f};
#pragma unroll
    for (int j = 0; j < 4; ++j) {
#pragma unroll
      for (int nf = 0; nf < 16; ++nf) mx[j] = fmaxf(mx[j], s1[nf][j]);
#pragma unroll
      for (int m = 1; m < 16; m <<= 1) mx[j] = fmaxf(mx[j], __shfl_xor(mx[j], m, 64));
    }
#pragma unroll
    for (int nf = 0; nf < 16; ++nf)
#pragma unroll
      for (int j = 0; j < 4; ++j) {
        const float e = __expf((s1[nf][j] - mx[j]) * 0.125f);
        s1[nf][j] = e;
        sum[j] += e;
      }
#pragma unroll
    for (int j = 0; j < 4; ++j)
#pragma unroll
      for (int m = 1; m < 16; m <<= 1) sum[j] += __shfl_xor(sum[j], m, 64);
    const float bs0 = __shfl(sum[0], ((l & 15) >> 2) << 4, 64);
    const float bs1 = __shfl(sum[1], ((l & 15) >> 2) << 4, 64);
    const float bs2 = __shfl(sum[2], ((l & 15) >> 2) << 4, 64);
    const float bs3 = __shfl(sum[3], ((l & 15) >> 2) << 4, 64);
    const float r01 = (l & 1) ? bs1 : bs0;
    const float r23 = (l & 1) ? bs3 : bs2;
    rs1 = 1.0f / ((l & 2) ? r23 : r01);
  }

  __syncthreads();  // ALL waves done reading K' before P overlays it (cross-wave)

  u16* Pw = smem + w * 4096;  // wave-private 16 rows x 512B
  const u16* vb = (const u16*)((const char*)smem + 32768);

  // ================= tile 0: P write -> PV -> epilogue =================
#pragma unroll
  for (int nf = 0; nf < 16; ++nf) {
    const int col = nf * 16 + (l & 15);
#pragma unroll
    for (int j = 0; j < 4; ++j) {
      const int row = (l >> 4) * 4 + j;
      *(u16*)((char*)Pw + row * 512 + ((col * 2) ^ (row << 4))) = f2bf(s0[nf][j]);
    }
  }
  // (no barrier: P is wave-private; same-wave ds ordering via lgkmcnt)
  {
    f32x4 o[4] = {};
#pragma unroll
    for (int kf = 0; kf < 8; ++kf) {
      const int q = l & 15;
      const bf16x8 pb = *(const bf16x8*)((const char*)Pw + q * 512 +
                                         ((kf * 64 + (l >> 4) * 16) ^ (q << 4)));
#pragma unroll
      for (int mf = 0; mf < 4; ++mf) {
        const int d = mf * 16 + (l & 15);
        const bf16x8 va = *(const bf16x8*)((const char*)vb + d * 512 +
                                           ((kf * 64 + (l >> 4) * 16) ^ ((d & 31) << 4)));
        o[mf] = __builtin_amdgcn_mfma_f32_16x16x32_bf16(va, pb, o[mf], 0, 0, 0);
      }
    }
#pragma unroll
    for (int mf = 0; mf < 4; ++mf) {
      const int d0 = mf * 16 + ((l >> 4) << 2);
      const int srow = b * 4096 + qbase + w * 16 + (l & 15);
      u16x4 ov = {f2bf(o[mf][0] * rs0), f2bf(o[mf][1] * rs0), f2bf(o[mf][2] * rs0),
                  f2bf(o[mf][3] * rs0)};
      *(u16x4*)(aout + (size_t)srow * 1024 + h * 64 + d0) = ov;
    }
  }

  // ================= tile 1: P overwrite (same-wave WAR) -> PV -> epilogue =========
#pragma unroll
  for (int nf = 0; nf < 16; ++nf) {
    const int col = nf * 16 + (l & 15);
#pragma unroll
    for (int j = 0; j < 4; ++j) {
      const int row = (l >> 4) * 4 + j;
      *(u16*)((char*)Pw + row * 512 + ((col * 2) ^ (row << 4))) = f2bf(s1[nf][j]);
    }
  }
  {
    f32x4 o[4] = {};
#pragma unroll
    for (int kf = 0; kf < 8; ++kf) {
      const int q = l & 15;
      const bf16x8 pb = *(const bf16x8*)((const char*)Pw + q * 512 +
                                         ((kf * 64 + (l >> 4) * 16) ^ (q << 4)));
#pragma unroll
      for (int mf = 0; mf < 4; ++mf) {
        const int d = mf * 16 + (l & 15);
        const bf16x8 va = *(const bf16x8*)((const char*)vb + d * 512 +
                                           ((kf * 64 + (l >> 4) * 16) ^ ((d & 31) << 4)));
        o[mf] = __builtin_amdgcn_mfma_f32_16x16x32_bf16(va, pb, o[mf], 0, 0, 0);
      }
    }
#pragma unroll
    for (int mf = 0; mf < 4; ++mf) {
      const int d0 = mf * 16 + ((l >> 4) << 2);
      const int srow = b * 4096 + qbase + 64 + w * 16 + (l & 15);
      u16x4 ov = {f2bf(o[mf][0] * rs1), f2bf(o[mf][1] * rs1), f2bf(o[mf][2] * rs1),
                  f2bf(o[mf][3] * rs1)};
      *(u16x4*)(aout + (size_t)srow * 1024 + h * 64 + d0) = ov;
    }
  }
}

// ---------------- host launch ----------------
extern "C" void kernel_launch(void* const* d_in, const int* in_sizes, int n_in,
                              void* d_out, int out_size, void* d_ws, size_t ws_size,
                              hipStream_t stream) {
  const float* hs = (const float*)d_in[0];
  const float* Wq = (const float*)d_in[1];
  const float* Wk = (const float*)d_in[2];
  const float* Wv = (const float*)d_in[3];
  const float* Wo = (const float*)d_in[4];
  const float* E = (const float*)d_in[5];
  const float* F = (const float*)d_in[6];

  // Workspace layout: peak 116 MiB (proven R2/R7/R11/R12).
  // aout ALIASES hsT2: hsT2 dead after proj64; aout first written by attn_kernel.
  char* ws = (char*)d_ws;
  u16* hs_bf = (u16*)(ws + 0);              // 32 MiB [16384][1024]
  u16* hsT2 = (u16*)(ws + 33554432);        // 32 MiB [4][1024][4096]
  u16* aout = hsT2;                         // 32 MiB [16384][1024] (alias)
  u16* qout = (u16*)(ws + 67108864);        // 32 MiB [16384][1024]
  u16* Wall = (u16*)(ws + 100663296);       // 8 MiB  Wq|Wk|Wv|Wo bf16
  u16* EFt = (u16*)(ws + 109051904);        // 4 MiB  [512][4096]
  u16* hsEF = (u16*)(ws + 113246208);       // 4 MiB  [4][512][1024]
  u16* kproj = (u16*)(ws + 117440512);      // 2 MiB  [4][256][1024]
  u16* vprojT = (u16*)(ws + 119537664);     // 2 MiB  [4][1024][256]

  conv_hs<<<dim3(512, 32), 256, 0, stream>>>(hs, hs_bf, hsT2);
  conv_w4<<<dim3(1024, 4), 256, 0, stream>>>(Wq, Wk, Wv, Wo, Wall);
  transpose_conv<<<dim3(128, 8), 256, 0, stream>>>(E, EFt);
  transpose_conv<<<dim3(128, 8), 256, 0, stream>>>(F, EFt + (size_t)256 * 4096);

  // q = hs @ Wq^T
  gemm_bt<1><<<dim3(128, 8), 256, 0, stream>>>(hs_bf, Wall, qout, 16384, 1024, 1024);
  // hsEF[b] = [E;F]^T @ hs[b]
  proj64<<<dim3(8, 8, 4), 256, 0, stream>>>(EFt, hsT2, hsEF);
  // kproj = hsE @ Wk^T ; vprojT = (hsF @ Wv^T)^T
  gemm_kv<<<dim3(32, 8), 256, 0, stream>>>(hsEF, Wall + 1048576, Wall + 2097152,
                                           kproj, vprojT);
  // attn: 2 q-tiles per block -> grid (32,16,4)
  attn_kernel<<<dim3(32, 16, 4), 256, 0, stream>>>(qout, kproj, vprojT, aout);
  // out = attn_out @ Wo^T (fp32 epilogue)
  gemm_bt<0><<<dim3(128, 8), 256, 0, stream>>>(aout, Wall + 3145728, d_out, 16384,
                                               1024, 1024);
}

// Round 14
// 377.304 us; speedup vs baseline: 1.1858x; 1.0093x over previous
//
#include <hip/hip_runtime.h>

typedef unsigned short u16;
typedef unsigned int u32;
typedef __attribute__((ext_vector_type(8))) __bf16 bf16x8;
typedef __attribute__((ext_vector_type(4))) float f32x4;
typedef __attribute__((ext_vector_type(8))) u16 u16x8;
typedef __attribute__((ext_vector_type(4))) u16 u16x4;

typedef const __attribute__((address_space(1))) u32* gas_p;
typedef __attribute__((address_space(3))) u32* las_p;

__device__ __forceinline__ void gload16(const void* g, void* l) {
  __builtin_amdgcn_global_load_lds((gas_p)g, (las_p)l, 16, 0, 0);
}

__device__ __forceinline__ u16 f2bf(float f) {
  u32 u = __builtin_bit_cast(u32, f);
  u32 r = (u + 0x7fffu + ((u >> 16) & 1u)) >> 16;
  return (u16)r;
}

// ---- fused hs conversion: hs [16384][1024] f32 -> hs_bf (same layout) + hsT2 [4][1024][4096] ----
__global__ __launch_bounds__(256) void conv_hs(const float* __restrict__ in,
                                               u16* __restrict__ out_row,
                                               u16* __restrict__ out_t) {
  __shared__ u16 t[32][34];
  const int r0 = blockIdx.x * 32, c0 = blockIdx.y * 32;
  const int lx = threadIdx.x & 31, ly = threadIdx.x >> 5;  // ly: 0..7
#pragma unroll
  for (int i = 0; i < 4; ++i) {
    const int r = r0 + ly + i * 8;
    const u16 v = f2bf(in[(size_t)r * 1024 + c0 + lx]);
    out_row[(size_t)r * 1024 + c0 + lx] = v;
    t[ly + i * 8][lx] = v;
  }
  __syncthreads();
  const int b = r0 >> 12, s0 = r0 & 4095;
#pragma unroll
  for (int i = 0; i < 4; ++i)
    out_t[((size_t)b * 1024 + c0 + ly + i * 8) * 4096 + s0 + lx] = t[lx][ly + i * 8];
}

// ---- 4 weight matrices fp32 -> bf16, one launch ----
__global__ __launch_bounds__(256) void conv_w4(const float* __restrict__ a,
                                               const float* __restrict__ b,
                                               const float* __restrict__ c,
                                               const float* __restrict__ d,
                                               u16* __restrict__ out) {
  const float* src = blockIdx.y == 0 ? a : blockIdx.y == 1 ? b : blockIdx.y == 2 ? c : d;
  const int i = (blockIdx.x * 256 + threadIdx.x) * 4;
  const float4 v = *(const float4*)(src + i);
  u16x4 o = {f2bf(v.x), f2bf(v.y), f2bf(v.z), f2bf(v.w)};
  *(u16x4*)(out + (size_t)blockIdx.y * 1048576 + i) = o;
}

// ---- transpose + convert: in [4096][256] f32 -> out [256][4096] bf16 ----
__global__ __launch_bounds__(256) void transpose_conv(const float* __restrict__ in,
                                                      u16* __restrict__ out) {
  const int R = 4096, Cc = 256;
  __shared__ float t[32][33];
  const int r0 = blockIdx.x * 32, c0 = blockIdx.y * 32;
  const int lx = threadIdx.x & 31, ly = threadIdx.x >> 5;
#pragma unroll
  for (int i = 0; i < 4; ++i)
    t[ly + i * 8][lx] = in[(size_t)(r0 + ly + i * 8) * Cc + c0 + lx];
  __syncthreads();
#pragma unroll
  for (int i = 0; i < 4; ++i)
    out[(size_t)(c0 + ly + i * 8) * R + r0 + lx] = f2bf(t[lx][ly + i * 8]);
}

// ---------------- bf16 GEMM: C[M][N] = A[M][K] * B[N][K]^T ----------------
// 128x128 tile, BK=64, 4 waves (2x2), 4x4 frags, 32 MFMA/wave per barrier pair.
template <int OUTBF>
__global__ __launch_bounds__(256) void gemm_bt(const u16* __restrict__ A,
                                               const u16* __restrict__ B,
                                               void* __restrict__ C, int M, int N,
                                               int K) {
  __shared__ u16 lds[2][128 * 64];  // 32 KiB total
  const int tid = threadIdx.x, l = tid & 63, w = tid >> 6;
  const int m0 = blockIdx.x * 128, n0 = blockIdx.y * 128;
  const int wr = w >> 1, wc = w & 1;
  f32x4 acc[4][4] = {};
  for (int k0 = 0; k0 < K; k0 += 64) {
#pragma unroll
    for (int i = 0; i < 4; ++i) {
      const int c = i * 256 + tid;
      const int row = c >> 3;
      const int scb = ((c & 7) << 4) ^ ((row & 7) << 4);
      gload16((const char*)A + ((size_t)(m0 + row) * K + k0) * 2 + scb,
              (char*)&lds[0][0] + (size_t)(i * 256 + w * 64) * 16);
      gload16((const char*)B + ((size_t)(n0 + row) * K + k0) * 2 + scb,
              (char*)&lds[1][0] + (size_t)(i * 256 + w * 64) * 16);
    }
    __syncthreads();
#pragma unroll
    for (int kk = 0; kk < 2; ++kk) {
      bf16x8 af[4], bf[4];
#pragma unroll
      for (int f = 0; f < 4; ++f) {
        const int ra = wr * 64 + f * 16 + (l & 15);
        af[f] = *(const bf16x8*)((const char*)&lds[0][0] + ra * 128 +
                                 (((l >> 4) * 16 + kk * 64) ^ ((ra & 7) << 4)));
        const int rb = wc * 64 + f * 16 + (l & 15);
        bf[f] = *(const bf16x8*)((const char*)&lds[1][0] + rb * 128 +
                                 (((l >> 4) * 16 + kk * 64) ^ ((rb & 7) << 4)));
      }
#pragma unroll
      for (int mf = 0; mf < 4; ++mf)
#pragma unroll
        for (int nf = 0; nf < 4; ++nf)
          acc[mf][nf] = __builtin_amdgcn_mfma_f32_16x16x32_bf16(af[mf], bf[nf],
                                                                acc[mf][nf], 0, 0, 0);
    }
    __syncthreads();
  }
#pragma unroll
  for (int mf = 0; mf < 4; ++mf) {
    const int rbase = m0 + wr * 64 + mf * 16 + ((l >> 4) << 2);
#pragma unroll
    for (int nf = 0; nf < 4; ++nf) {
      const int cc = n0 + wc * 64 + nf * 16 + (l & 15);
#pragma unroll
      for (int j = 0; j < 4; ++j) {
        if (OUTBF)
          ((u16*)C)[(size_t)(rbase + j) * N + cc] = f2bf(acc[mf][nf][j]);
        else
          ((float*)C)[(size_t)(rbase + j) * N + cc] = acc[mf][nf][j];
      }
    }
  }
}

// ---- Linformer projection as pure BT GEMM: hsEF[b][m][n] = sum_k EFt[m][k]*hsT2[b][n][k] ----
// 64x128 tile, BK=64, 4 waves (2x2), 2x4 frags.
__global__ __launch_bounds__(256) void proj64(const u16* __restrict__ EFt,
                                              const u16* __restrict__ hsT2,
                                              u16* __restrict__ hsEF) {
  __shared__ u16 lA[64 * 64], lB[128 * 64];  // 8 KiB + 16 KiB
  const int tid = threadIdx.x, l = tid & 63, w = tid >> 6;
  const int m0 = blockIdx.x * 64, n0 = blockIdx.y * 128, b = blockIdx.z;
  const u16* Bp = hsT2 + (size_t)b * 1024 * 4096;
  const int wr = w >> 1, wc = w & 1;
  f32x4 acc[2][4] = {};
  for (int k0 = 0; k0 < 4096; k0 += 64) {
#pragma unroll
    for (int i = 0; i < 2; ++i) {  // A: 64 rows x 128B = 512 chunks
      const int c = i * 256 + tid;
      const int row = c >> 3;
      const int scb = ((c & 7) << 4) ^ ((row & 7) << 4);
      gload16((const char*)EFt + ((size_t)(m0 + row) * 4096 + k0) * 2 + scb,
              (char*)lA + (size_t)(i * 256 + w * 64) * 16);
    }
#pragma unroll
    for (int i = 0; i < 4; ++i) {  // B: 128 rows x 128B = 1024 chunks
      const int c = i * 256 + tid;
      const int row = c >> 3;
      const int scb = ((c & 7) << 4) ^ ((row & 7) << 4);
      gload16((const char*)Bp + ((size_t)(n0 + row) * 4096 + k0) * 2 + scb,
              (char*)lB + (size_t)(i * 256 + w * 64) * 16);
    }
    __syncthreads();
#pragma unroll
    for (int kk = 0; kk < 2; ++kk) {
      bf16x8 af[2], bf[4];
#pragma unroll
      for (int f = 0; f < 2; ++f) {
        const int ra = wr * 32 + f * 16 + (l & 15);
        af[f] = *(const bf16x8*)((const char*)lA + ra * 128 +
                                 (((l >> 4) * 16 + kk * 64) ^ ((ra & 7) << 4)));
      }
#pragma unroll
      for (int f = 0; f < 4; ++f) {
        const int rb = wc * 64 + f * 16 + (l & 15);
        bf[f] = *(const bf16x8*)((const char*)lB + rb * 128 +
                                 (((l >> 4) * 16 + kk * 64) ^ ((rb & 7) << 4)));
      }
#pragma unroll
      for (int mf = 0; mf < 2; ++mf)
#pragma unroll
        for (int nf = 0; nf < 4; ++nf)
          acc[mf][nf] = __builtin_amdgcn_mfma_f32_16x16x32_bf16(af[mf], bf[nf],
                                                                acc[mf][nf], 0, 0, 0);
    }
    __syncthreads();
  }
#pragma unroll
  for (int mf = 0; mf < 2; ++mf) {
    const int rbase = m0 + wr * 32 + mf * 16 + ((l >> 4) << 2);
#pragma unroll
    for (int nf = 0; nf < 4; ++nf) {
      const int cc = n0 + wc * 64 + nf * 16 + (l & 15);
#pragma unroll
      for (int j = 0; j < 4; ++j)
        hsEF[((size_t)b * 512 + rbase + j) * 1024 + cc] = f2bf(acc[mf][nf][j]);
    }
  }
}

// ---- combined K'/V' weight application: A = hsEF flat [2048][1024], B = Wk or Wv ----
// 64x128 tile, BK=64. grid (32,8)=256 blocks.
__global__ __launch_bounds__(256) void gemm_kv(const u16* __restrict__ hsEF,
                                               const u16* __restrict__ Wk,
                                               const u16* __restrict__ Wv,
                                               u16* __restrict__ kproj,
                                               u16* __restrict__ vprojT) {
  __shared__ u16 lA[64 * 64], lB[128 * 64];
  const int tid = threadIdx.x, l = tid & 63, w = tid >> 6;
  const int m0 = blockIdx.x * 64, n0 = blockIdx.y * 128;
  const int b = m0 >> 9, half = (m0 >> 8) & 1;
  const u16* Bp = half ? Wv : Wk;
  const int wr = w >> 1, wc = w & 1;
  f32x4 acc[2][4] = {};
  for (int k0 = 0; k0 < 1024; k0 += 64) {
#pragma unroll
    for (int i = 0; i < 2; ++i) {
      const int c = i * 256 + tid;
      const int row = c >> 3;
      const int scb = ((c & 7) << 4) ^ ((row & 7) << 4);
      gload16((const char*)hsEF + ((size_t)(m0 + row) * 1024 + k0) * 2 + scb,
              (char*)lA + (size_t)(i * 256 + w * 64) * 16);
    }
#pragma unroll
    for (int i = 0; i < 4; ++i) {
      const int c = i * 256 + tid;
      const int row = c >> 3;
      const int scb = ((c & 7) << 4) ^ ((row & 7) << 4);
      gload16((const char*)Bp + ((size_t)(n0 + row) * 1024 + k0) * 2 + scb,
              (char*)lB + (size_t)(i * 256 + w * 64) * 16);
    }
    __syncthreads();
#pragma unroll
    for (int kk = 0; kk < 2; ++kk) {
      bf16x8 af[2], bf[4];
#pragma unroll
      for (int f = 0; f < 2; ++f) {
        const int ra = wr * 32 + f * 16 + (l & 15);
        af[f] = *(const bf16x8*)((const char*)lA + ra * 128 +
                                 (((l >> 4) * 16 + kk * 64) ^ ((ra & 7) << 4)));
      }
#pragma unroll
      for (int f = 0; f < 4; ++f) {
        const int rb = wc * 64 + f * 16 + (l & 15);
        bf[f] = *(const bf16x8*)((const char*)lB + rb * 128 +
                                 (((l >> 4) * 16 + kk * 64) ^ ((rb & 7) << 4)));
      }
#pragma unroll
      for (int mf = 0; mf < 2; ++mf)
#pragma unroll
        for (int nf = 0; nf < 4; ++nf)
          acc[mf][nf] = __builtin_amdgcn_mfma_f32_16x16x32_bf16(af[mf], bf[nf],
                                                                acc[mf][nf], 0, 0, 0);
    }
    __syncthreads();
  }
#pragma unroll
  for (int mf = 0; mf < 2; ++mf) {
    const int kp0 = (m0 & 255) + wr * 32 + mf * 16 + ((l >> 4) << 2);
#pragma unroll
    for (int nf = 0; nf < 4; ++nf) {
      const int n = n0 + wc * 64 + nf * 16 + (l & 15);
      if (!half) {
#pragma unroll
        for (int j = 0; j < 4; ++j)
          kproj[((size_t)b * 256 + kp0 + j) * 1024 + n] = f2bf(acc[mf][nf][j]);
      } else {
        u16x4 o = {f2bf(acc[mf][nf][0]), f2bf(acc[mf][nf][1]), f2bf(acc[mf][nf][2]),
                   f2bf(acc[mf][nf][3])};
        *(u16x4*)(vprojT + ((size_t)b * 1024 + n) * 256 + kp0) = o;
      }
    }
  }
}

// ---------------- fused attention v4: R11 structure + proven micro-deltas ----------------
// 1 q-tile (64 rows) per block, staged K'/V' (R11, 64 µs proven).
// Deltas: deferred normalization (proven R12/R13), exp2f fused constant (exact),
// no barrier after wave-private P write (proven R13).
__global__ __launch_bounds__(256) void attn_kernel(const u16* __restrict__ qmat,
                                                   const u16* __restrict__ kproj,
                                                   const u16* __restrict__ vprojT,
                                                   u16* __restrict__ aout) {
  __shared__ u16 smem[32768];  // 64KB: [0,32KB) K'/P union, [32KB,64KB) V'^T
  const int tid = threadIdx.x, l = tid & 63, w = tid >> 6;
  const int qt = blockIdx.x, h = blockIdx.y, b = blockIdx.z;
  const int qbase = qt * 64;

#pragma unroll
  for (int i = 0; i < 8; ++i) {  // K' [256][128B], swz (row&7)<<4
    const int c = i * 256 + tid;
    const int row = c >> 3;
    const int scb = ((c & 7) << 4) ^ ((row & 7) << 4);
    gload16((const char*)kproj + (((size_t)(b * 256 + row)) * 1024 + h * 64) * 2 + scb,
            (char*)smem + (size_t)(i * 256 + w * 64) * 16);
  }
#pragma unroll
  for (int i = 0; i < 8; ++i) {  // V'^T [64][512B], swz (d&31)<<4
    const int c = i * 256 + tid;
    const int d = c >> 5;
    const int scb = ((c & 31) << 4) ^ ((d & 31) << 4);
    gload16((const char*)vprojT + ((size_t)(b * 1024 + h * 64 + d)) * 256 * 2 + scb,
            (char*)smem + 32768 + (size_t)(i * 256 + w * 64) * 16);
  }
  __syncthreads();

  const u16* qrow =
      qmat + ((size_t)(b * 4096 + qbase + w * 16 + (l & 15))) * 1024 + h * 64;
  bf16x8 qa[2];
#pragma unroll
  for (int kf = 0; kf < 2; ++kf)
    qa[kf] = *(const bf16x8*)(qrow + kf * 32 + (l >> 4) * 8);

  f32x4 s[16] = {};
#pragma unroll
  for (int nf = 0; nf < 16; ++nf) {
    const int kr = nf * 16 + (l & 15);
#pragma unroll
    for (int kf = 0; kf < 2; ++kf) {
      const bf16x8 kb = *(const bf16x8*)((const char*)smem + kr * 128 +
                                         ((kf * 64 + (l >> 4) * 16) ^ ((kr & 7) << 4)));
      s[nf] = __builtin_amdgcn_mfma_f32_16x16x32_bf16(qa[kf], kb, s[nf], 0, 0, 0);
    }
  }

  // ---- wave-parallel softmax, UNNORMALIZED P; exp2 with fused 0.125*log2(e) ----
  float mx[4] = {-1e30f, -1e30f, -1e30f, -1e30f}, sum[4] = {0.f, 0.f, 0.f, 0.f};
#pragma unroll
  for (int j = 0; j < 4; ++j) {
#pragma unroll
    for (int nf = 0; nf < 16; ++nf) mx[j] = fmaxf(mx[j], s[nf][j]);
#pragma unroll
    for (int m = 1; m < 16; m <<= 1) mx[j] = fmaxf(mx[j], __shfl_xor(mx[j], m, 64));
  }
#pragma unroll
  for (int nf = 0; nf < 16; ++nf)
#pragma unroll
    for (int j = 0; j < 4; ++j) {
      const float e = exp2f((s[nf][j] - mx[j]) * 0.18033688011f);
      s[nf][j] = e;
      sum[j] += e;
    }
#pragma unroll
  for (int j = 0; j < 4; ++j)
#pragma unroll
    for (int m = 1; m < 16; m <<= 1) sum[j] += __shfl_xor(sum[j], m, 64);

  // rsum for this lane's epilogue q-row (q = l&15), proven broadcast (R12/R13)
  const float bs0 = __shfl(sum[0], ((l & 15) >> 2) << 4, 64);
  const float bs1 = __shfl(sum[1], ((l & 15) >> 2) << 4, 64);
  const float bs2 = __shfl(sum[2], ((l & 15) >> 2) << 4, 64);
  const float bs3 = __shfl(sum[3], ((l & 15) >> 2) << 4, 64);
  const float r01 = (l & 1) ? bs1 : bs0;
  const float r23 = (l & 1) ? bs3 : bs2;
  const float rs = 1.0f / ((l & 2) ? r23 : r01);

  __syncthreads();  // ALL waves done reading K' before P overlays it (cross-wave)

  // ---- write unnormalized P (bf16) into per-wave region of the K' union ----
  u16* Pw = smem + w * 4096;  // 16 rows x 512B, wave-private
#pragma unroll
  for (int nf = 0; nf < 16; ++nf) {
    const int col = nf * 16 + (l & 15);
#pragma unroll
    for (int j = 0; j < 4; ++j) {
      const int row = (l >> 4) * 4 + j;
      *(u16*)((char*)Pw + row * 512 + ((col * 2) ^ (row << 4))) = f2bf(s[nf][j]);
    }
  }
  // no barrier: P wave-private; same-wave ds ordering via lgkmcnt (proven R13)

  // ---- O^T[d][q] = V'^T * P^T : 4 d-frags x 8 k-steps ----
  const u16* vb = (const u16*)((const char*)smem + 32768);
  f32x4 o[4] = {};
#pragma unroll
  for (int kf = 0; kf < 8; ++kf) {
    const int q = l & 15;
    const bf16x8 pb = *(const bf16x8*)((const char*)Pw + q * 512 +
                                       ((kf * 64 + (l >> 4) * 16) ^ (q << 4)));
#pragma unroll
    for (int mf = 0; mf < 4; ++mf) {
      const int d = mf * 16 + (l & 15);
      const bf16x8 va = *(const bf16x8*)((const char*)vb + d * 512 +
                                         ((kf * 64 + (l >> 4) * 16) ^ ((d & 31) << 4)));
      o[mf] = __builtin_amdgcn_mfma_f32_16x16x32_bf16(va, pb, o[mf], 0, 0, 0);
    }
  }

  // ---- epilogue: deferred normalization, 8B stores ----
#pragma unroll
  for (int mf = 0; mf < 4; ++mf) {
    const int d0 = mf * 16 + ((l >> 4) << 2);
    const int srow = b * 4096 + qbase + w * 16 + (l & 15);
    u16x4 ov = {f2bf(o[mf][0] * rs), f2bf(o[mf][1] * rs), f2bf(o[mf][2] * rs),
                f2bf(o[mf][3] * rs)};
    *(u16x4*)(aout + (size_t)srow * 1024 + h * 64 + d0) = ov;
  }
}

// ---------------- host launch ----------------
extern "C" void kernel_launch(void* const* d_in, const int* in_sizes, int n_in,
                              void* d_out, int out_size, void* d_ws, size_t ws_size,
                              hipStream_t stream) {
  const float* hs = (const float*)d_in[0];
  const float* Wq = (const float*)d_in[1];
  const float* Wk = (const float*)d_in[2];
  const float* Wv = (const float*)d_in[3];
  const float* Wo = (const float*)d_in[4];
  const float* E = (const float*)d_in[5];
  const float* F = (const float*)d_in[6];

  // Workspace layout: peak 116 MiB (proven R2/R7/R11-R13).
  // aout ALIASES hsT2: hsT2 dead after proj64; aout first written by attn_kernel.
  char* ws = (char*)d_ws;
  u16* hs_bf = (u16*)(ws + 0);              // 32 MiB [16384][1024]
  u16* hsT2 = (u16*)(ws + 33554432);        // 32 MiB [4][1024][4096]
  u16* aout = hsT2;                         // 32 MiB [16384][1024] (alias)
  u16* qout = (u16*)(ws + 67108864);        // 32 MiB [16384][1024]
  u16* Wall = (u16*)(ws + 100663296);       // 8 MiB  Wq|Wk|Wv|Wo bf16
  u16* EFt = (u16*)(ws + 109051904);        // 4 MiB  [512][4096]
  u16* hsEF = (u16*)(ws + 113246208);       // 4 MiB  [4][512][1024]
  u16* kproj = (u16*)(ws + 117440512);      // 2 MiB  [4][256][1024]
  u16* vprojT = (u16*)(ws + 119537664);     // 2 MiB  [4][1024][256]

  conv_hs<<<dim3(512, 32), 256, 0, stream>>>(hs, hs_bf, hsT2);
  conv_w4<<<dim3(1024, 4), 256, 0, stream>>>(Wq, Wk, Wv, Wo, Wall);
  transpose_conv<<<dim3(128, 8), 256, 0, stream>>>(E, EFt);
  transpose_conv<<<dim3(128, 8), 256, 0, stream>>>(F, EFt + (size_t)256 * 4096);

  // q = hs @ Wq^T
  gemm_bt<1><<<dim3(128, 8), 256, 0, stream>>>(hs_bf, Wall, qout, 16384, 1024, 1024);
  // hsEF[b] = [E;F]^T @ hs[b]
  proj64<<<dim3(8, 8, 4), 256, 0, stream>>>(EFt, hsT2, hsEF);
  // kproj = hsE @ Wk^T ; vprojT = (hsF @ Wv^T)^T
  gemm_kv<<<dim3(32, 8), 256, 0, stream>>>(hsEF, Wall + 1048576, Wall + 2097152,
                                           kproj, vprojT);
  // attn: 1 q-tile per block (R11 grid)
  attn_kernel<<<dim3(64, 16, 4), 256, 0, stream>>>(qout, kproj, vprojT, aout);
  // out = attn_out @ Wo^T (fp32 epilogue)
  gemm_bt<0><<<dim3(128, 8), 256, 0, stream>>>(aout, Wall + 3145728, d_out, 16384,
                                               1024, 1024);
}